// Round 16
// baseline (1787.476 us; speedup 1.0000x reference)
//
#include <hip/hip_runtime.h>
#include <cstdint>
#include <math.h>

// GPT-2 forward, MI355X. B=2, T=1024, D=1024, NH=16, HD=64, L=12, F=4096, V=50257.
// fp32 residual; bf16 MFMA GEMMs (16x16x32, 2-deep counted-vmcnt pipeline, T2 XOR
// swizzle, setprio, XCD swizzle; BN=64 for qkv -> 3 blocks/CU full round, BN=128
// elsewhere); LDS-bounce epilogue with fused V-transpose; bf16 split-K partials;
// head-major qkv; reg-staged attn; wtrans+bias-permute fused into LN1.

using u16 = unsigned short;
using bf16x8 = __attribute__((ext_vector_type(8))) short;
using f32x4 = __attribute__((ext_vector_type(4))) float;

#define GLDS16(g, l)                                                        \
  __builtin_amdgcn_global_load_lds(                                         \
      (const __attribute__((address_space(1))) void*)(g),                   \
      (__attribute__((address_space(3))) void*)(l), 16, 0, 0)

__device__ __forceinline__ u16 f2bf(float f) {
  union { float f; unsigned u; } t; t.f = f;
  unsigned r = t.u + 0x7fffu + ((t.u >> 16) & 1u);
  return (u16)(r >> 16);
}
__device__ __forceinline__ float bf2f(u16 v) {
  union { unsigned u; float f; } t; t.u = ((unsigned)v) << 16;
  return t.f;
}

// A&S 7.1.26, |err| <= 1.5e-7
__device__ __forceinline__ float fast_erf(float x) {
  float ax = fabsf(x);
  float t = 1.f / (1.f + 0.3275911f * ax);
  float y = t * (0.254829592f +
            t * (-0.284496736f +
            t * (1.421413741f +
            t * (-1.453152027f +
            t * 1.061405429f))));
  float r = 1.f - y * __expf(-ax * ax);
  return copysignf(r, x);
}

#define DD 1024
#define TTT 1024
#define MR 2048     // B*T
#define FFF 4096
#define VVV 50257

// ---------------- embedding ----------------
__global__ __launch_bounds__(256) void k_embed(const int* __restrict__ tokens,
                                               const float* __restrict__ wte,
                                               const float* __restrict__ wpe,
                                               float* __restrict__ x) {
  int m = blockIdx.x, d = threadIdx.x * 4;
  int t = m & (TTT - 1);
  int tok = tokens[m];
  const float4 a = *(const float4*)(wte + (size_t)tok * DD + d);
  const float4 p = *(const float4*)(wpe + (size_t)t * DD + d);
  float4 o; o.x = a.x + p.x; o.y = a.y + p.y; o.z = a.z + p.z; o.w = a.w + p.w;
  *(float4*)(x + (size_t)m * DD + d) = o;
}

// ---------------- add bf16 partials + layernorm -> bf16 (wave per row) ----------------
__device__ __forceinline__ void addln_body(float* __restrict__ x,
                                           const u16* __restrict__ pp, int npart,
                                           const float* __restrict__ w,
                                           const float* __restrict__ b,
                                           u16* __restrict__ out, int blk) {
  const int wid = threadIdx.x >> 6, lane = threadIdx.x & 63;
  const int m = blk * 4 + wid;
  float* row = x + (size_t)m * DD;
  float4 v[4];
  float s = 0.f, q = 0.f;
#pragma unroll
  for (int j = 0; j < 4; ++j) {
    v[j] = *(const float4*)(row + j * 256 + lane * 4);
#pragma unroll 4
    for (int p = 0; p < npart; ++p) {
      uint64_t pv = *(const uint64_t*)(pp + (size_t)p * MR * DD + (size_t)m * DD + j * 256 + lane * 4);
      v[j].x += bf2f((u16)(pv));
      v[j].y += bf2f((u16)(pv >> 16));
      v[j].z += bf2f((u16)(pv >> 32));
      v[j].w += bf2f((u16)(pv >> 48));
    }
    if (npart) *(float4*)(row + j * 256 + lane * 4) = v[j];
    s += v[j].x + v[j].y + v[j].z + v[j].w;
    q += v[j].x * v[j].x + v[j].y * v[j].y + v[j].z * v[j].z + v[j].w * v[j].w;
  }
#pragma unroll
  for (int off = 1; off < 64; off <<= 1) { s += __shfl_xor(s, off); q += __shfl_xor(q, off); }
  float mean = s * (1.f / DD);
  float var = q * (1.f / DD) - mean * mean;
  float rs = rsqrtf(var + 1e-5f);
#pragma unroll
  for (int j = 0; j < 4; ++j) {
    const float4 wv = *(const float4*)(w + j * 256 + lane * 4);
    const float4 bv = *(const float4*)(b + j * 256 + lane * 4);
    u16 o[4];
    o[0] = f2bf((v[j].x - mean) * rs * wv.x + bv.x);
    o[1] = f2bf((v[j].y - mean) * rs * wv.y + bv.y);
    o[2] = f2bf((v[j].z - mean) * rs * wv.z + bv.z);
    o[3] = f2bf((v[j].w - mean) * rs * wv.w + bv.w);
    *(uint64_t*)(out + (size_t)m * DD + j * 256 + lane * 4) = *(uint64_t*)o;
  }
}

__global__ __launch_bounds__(256) void k_addln(float* __restrict__ x,
                                               const u16* __restrict__ pp, int npart,
                                               const float* __restrict__ w,
                                               const float* __restrict__ b,
                                               u16* __restrict__ out) {
  addln_body(x, pp, npart, w, b, out, blockIdx.x);
}

// ---------------- weight transpose body: fp32[K,N] -> bf16[N,K] ----------------
// atw rows are stored head-major-permuted: c = part*1024 + n*64 + h.
__device__ __forceinline__ void wtrans_body(const float* __restrict__ atw,
                                            const float* __restrict__ apw,
                                            const float* __restrict__ fcw,
                                            const float* __restrict__ pjw,
                                            u16* __restrict__ wt, int id) {
  __shared__ u16 tb[64][72];
  const float* W; u16* Wt; int K, N, local, kts; bool perm = false;
  if (id < 768)       { W = atw; Wt = wt;           K = 1024; N = 3072; local = id;        kts = 4; perm = true; }
  else if (id < 1024) { W = apw; Wt = wt + 3145728; K = 1024; N = 1024; local = id - 768;  kts = 4; }
  else if (id < 2048) { W = fcw; Wt = wt + 4194304; K = 1024; N = 4096; local = id - 1024; kts = 4; }
  else                { W = pjw; Wt = wt + 8388608; K = 4096; N = 1024; local = id - 2048; kts = 6; }
  const int k0 = (local & ((1 << kts) - 1)) * 64, n0 = (local >> kts) * 64;
  const int tid = threadIdx.x;
  const int rr = tid >> 4, c4 = (tid & 15) * 4;
#pragma unroll
  for (int i = 0; i < 4; ++i) {
    const int r = rr + i * 16;
    const float4 v = *(const float4*)(W + (size_t)(k0 + r) * N + n0 + c4);
    tb[c4 + 0][r] = f2bf(v.x);
    tb[c4 + 1][r] = f2bf(v.y);
    tb[c4 + 2][r] = f2bf(v.z);
    tb[c4 + 3][r] = f2bf(v.w);
  }
  __syncthreads();
  const int n = tid >> 3, k8 = (tid & 7) * 8;
#pragma unroll
  for (int s = 0; s < 2; ++s) {
    u16 o[8];
#pragma unroll
    for (int j = 0; j < 8; ++j) o[j] = tb[n + s * 32][k8 + j];
    int orow = n0 + n + s * 32;
    if (perm) {
      int part = orow >> 10, w = orow & 1023;
      orow = part * 1024 + (w & 15) * 64 + (w >> 4);
    }
    *(bf16x8*)(Wt + (size_t)orow * K + k0 + k8) = *(bf16x8*)o;
  }
}

// ---------------- fused prep: [0,512) add+LN1, 3584 bias-permute, else wtrans ----------------
__global__ __launch_bounds__(256) void k_prep(float* __restrict__ x,
                                              const u16* __restrict__ pp, int npart,
                                              const float* __restrict__ w,
                                              const float* __restrict__ b,
                                              u16* __restrict__ out,
                                              const float* __restrict__ atw,
                                              const float* __restrict__ apw,
                                              const float* __restrict__ fcw,
                                              const float* __restrict__ pjw,
                                              u16* __restrict__ wt,
                                              const float* __restrict__ ab,
                                              float* __restrict__ pbias) {
  if (blockIdx.x < 512) {
    addln_body(x, pp, npart, w, b, out, blockIdx.x);
  } else if (blockIdx.x == 3584) {
    for (int c = threadIdx.x; c < 3072; c += 256) {
      int part = c >> 10, ww = c & 1023;
      pbias[c] = ab[part * 1024 + (ww & 63) * 16 + (ww >> 6)];
    }
  } else {
    wtrans_body(atw, apw, fcw, pjw, wt, blockIdx.x - 512);
  }
}

// ---------------- GEMM: out = A[M,K] * Bt[N,K]^T + bias ----------------
// BN template: 64 (qkv, 48 KB LDS -> 3 blocks/CU) or 128 (others, 64 KB -> 2/CU).
// EPI 0: bf16 out + fused V-transpose (BN=64, by>=32 -> Vt, one head per tile);
// EPI 2: gelu->bf16; EPI 4: bf16 partial (split-K, bias bz==0).
template <int EPI, int BN>
__global__ __launch_bounds__(256) void k_gemm(const u16* __restrict__ A,
                                              const u16* __restrict__ Bt,
                                              const float* __restrict__ bias,
                                              u16* __restrict__ outb,
                                              u16* __restrict__ pp,
                                              u16* __restrict__ vt,
                                              int M, int N, int K, int KC) {
  constexpr int JF = BN / 32;          // 16-col frags per wave (per wc half)
  constexpr int BITS = BN / 32;        // B staging iterations (32 rows each)
  constexpr int EBS = BN + 4;          // epilogue LDS row stride
  __shared__ u16 As[2][128 * 64];
  __shared__ u16 Bs[2][BN * 64];
  // bijective XCD swizzle (m204)
  const int nbx = gridDim.x, nby = gridDim.y;
  const int nwg = nbx * nby * gridDim.z;
  const int orig = blockIdx.x + nbx * (blockIdx.y + nby * blockIdx.z);
  const int qq = nwg >> 3, rr = nwg & 7;
  const int xcd = orig & 7, pos = orig >> 3;
  const int wg = (xcd < rr ? xcd * (qq + 1) : rr * (qq + 1) + (xcd - rr) * qq) + pos;
  const int bx = wg % nbx;
  const int tmpw = wg / nbx;
  const int by = tmpw % nby, bz = tmpw / nby;

  const int tid = threadIdx.x;
  const int lane = tid & 63, wid = tid >> 6;
  const int wr = wid >> 1, wc = wid & 1;
  const int l15 = lane & 15, l4 = lane >> 4;
  const int sx = l15 & 7;
  const int m0 = bx * 128, n0 = by * BN;
  f32x4 acc[4][JF] = {};

  const int srow = tid >> 3;
  const int scol = (((tid & 7) ^ (srow & 7)) * 8);  // inverse swizzle on source
  const int k0beg = bz * KC;
  const int nt = KC >> 6;

  const u16* Ap = A + (size_t)(m0 + srow) * K + scol;
  const u16* Bp = Bt + (size_t)(n0 + srow) * K + scol;

#define STAGE(buf, k0)                                                      \
  {                                                                         \
    _Pragma("unroll")                                                       \
    for (int it = 0; it < 4; ++it)                                          \
      GLDS16(Ap + (size_t)it * 32 * K + (k0), (char*)As[buf] + it * 4096 + tid * 16); \
    _Pragma("unroll")                                                       \
    for (int it = 0; it < BITS; ++it)                                       \
      GLDS16(Bp + (size_t)it * 32 * K + (k0), (char*)Bs[buf] + it * 4096 + tid * 16); \
  }

  STAGE(0, k0beg);
  for (int t = 0; t < nt; ++t) {
    if (t + 1 < nt) {
      STAGE((t + 1) & 1, k0beg + (t + 1) * 64);
      if (BN == 64) {
        asm volatile("s_waitcnt vmcnt(6)" ::: "memory");
      } else {
        asm volatile("s_waitcnt vmcnt(8)" ::: "memory");
      }
    } else {
      asm volatile("s_waitcnt vmcnt(0)" ::: "memory");
    }
    __builtin_amdgcn_sched_barrier(0);
    __builtin_amdgcn_s_barrier();
    __builtin_amdgcn_sched_barrier(0);
    const u16* Ab = As[t & 1];
    const u16* Bb = Bs[t & 1];
#pragma unroll
    for (int ks = 0; ks < 2; ++ks) {
      const int ch = ((ks * 4 + l4) ^ sx) * 8;
      bf16x8 af[4], bfr[JF];
#pragma unroll
      for (int i = 0; i < 4; ++i)
        af[i] = *(const bf16x8*)(Ab + (wr * 64 + i * 16 + l15) * 64 + ch);
#pragma unroll
      for (int j = 0; j < JF; ++j)
        bfr[j] = *(const bf16x8*)(Bb + (wc * (BN / 2) + j * 16 + l15) * 64 + ch);
      __builtin_amdgcn_s_setprio(1);
#pragma unroll
      for (int i = 0; i < 4; ++i)
#pragma unroll
        for (int j = 0; j < JF; ++j)
          acc[i][j] = __builtin_amdgcn_mfma_f32_16x16x32_bf16(af[i], bfr[j], acc[i][j], 0, 0, 0);
      __builtin_amdgcn_s_setprio(0);
    }
    __builtin_amdgcn_sched_barrier(0);
    __builtin_amdgcn_s_barrier();
    __builtin_amdgcn_sched_barrier(0);
  }
#undef STAGE
  // ---- LDS-bounce epilogue (staging buffers are free past the final barrier) ----
  u16* eb = (u16*)As;  // [128][EBS] bf16
#pragma unroll
  for (int j = 0; j < JF; ++j) {
    const int col = wc * (BN / 2) + j * 16 + l15;
    const float bs = (EPI == 4 && bz != 0) ? 0.f : bias[n0 + col];
#pragma unroll
    for (int i = 0; i < 4; ++i) {
#pragma unroll
      for (int r = 0; r < 4; ++r) {
        const int row = wr * 64 + i * 16 + l4 * 4 + r;
        float v = acc[i][j][r] + bs;
        if (EPI == 2) v = 0.5f * v * (1.f + fast_erf(v * 0.70710678118f));
        eb[row * EBS + col] = f2bf(v);
      }
    }
  }
  __syncthreads();
  if (EPI == 0 && BN == 64 && by >= 32) {
    // fused V-transpose: this tile is one head's V columns; write Vt[bn*64+h][t]
    const int b = m0 >> 10, t0 = m0 & 1023;
    const int n = by - 32;
    const int col = tid & 63;           // h
    const int tseg = tid >> 6;          // 0..3, 32 t each
    u16* vdst = vt + (((size_t)(b * 16 + n)) * 64 + col) * TTT + t0 + tseg * 32;
#pragma unroll
    for (int s = 0; s < 4; ++s) {
      u16 o[8];
#pragma unroll
      for (int k = 0; k < 8; ++k) o[k] = eb[(tseg * 32 + s * 8 + k) * EBS + col];
      *(bf16x8*)(vdst + s * 8) = *(bf16x8*)o;
    }
  } else {
    const int erow = tid >> 1;
    const int ecol0 = (tid & 1) * (BN / 2);
    u16* gout = (EPI == 4) ? (pp + (size_t)bz * M * N) : outb;
    u16* gdst = gout + (size_t)(m0 + erow) * N + n0 + ecol0;
    const u16* esrc = eb + erow * EBS + ecol0;
#pragma unroll
    for (int c = 0; c < BN / 16; ++c)
      *(bf16x8*)(gdst + c * 8) = *(const bf16x8*)(esrc + c * 8);
  }
}

// ---------------- flash attention (causal), T14 reg-staged K/V ----------------
__global__ __launch_bounds__(256) void k_attn(const u16* __restrict__ qkv,
                                              const u16* __restrict__ Vt,
                                              u16* __restrict__ attout) {
  __shared__ u16 Ks[128 * 64];
  __shared__ u16 Vs[64 * 128];
  __shared__ u16 Ps[4][16 * 136];

  const int tid = threadIdx.x;
  const int lane = tid & 63, wid = tid >> 6;
  const int l15 = lane & 15, l4 = lane >> 4;
  const int bn = blockIdx.x;                 // b*16 + n
  const int qtr = 15 - (int)blockIdx.y;      // heavy tiles first
  const int q0 = qtr * 64;
  const int b = bn >> 4, nh = bn & 15;
  const char* Kg0 = (const char*)(qkv + (size_t)b * TTT * 3072 + 1024 + nh * 64);
  const char* Vg0 = (const char*)(Vt + (size_t)bn * 64 * TTT);
  const float CEXP = 0.125f * 1.44269504f;   // fold scale into exp2

  int KL[4], Kro[4], Kcb[4], VL[4], Voff[4];
#pragma unroll
  for (int it = 0; it < 4; ++it) {
    int L = it * 4096 + tid * 16;
    KL[it] = L;
    int Ls = L ^ (((L >> 7) & 7) << 4);
    Kro[it] = Ls >> 7; Kcb[it] = Ls & 127;
    VL[it] = L;
    int Ls2 = L ^ (((L >> 8) & 7) << 4);
    Voff[it] = (Ls2 >> 8) * 2048 + (Ls2 & 255);
  }

  const int qrow = q0 + wid * 16 + l15;
  const u16* qsrc = qkv + (size_t)(b * TTT + qrow) * 3072 + nh * 64;
  bf16x8 aq[2];
#pragma unroll
  for (int ks = 0; ks < 2; ++ks)
    aq[ks] = *(const bf16x8*)(qsrc + ks * 32 + l4 * 8);

  float m_run[4], l_part[4];
  f32x4 o[4] = {};
#pragma unroll
  for (int r = 0; r < 4; ++r) { m_run[r] = -1e30f; l_part[r] = 0.f; }

  const int ntk = (qtr >> 1) + 1;
  bf16x8 kreg[4], vreg[4];
#pragma unroll
  for (int it = 0; it < 4; ++it) {
    kreg[it] = *(const bf16x8*)(Kg0 + (size_t)Kro[it] * 6144 + Kcb[it]);
    vreg[it] = *(const bf16x8*)(Vg0 + Voff[it]);
  }
  for (int kt = 0; kt < ntk; ++kt) {
#pragma unroll
    for (int it = 0; it < 4; ++it) {
      *(bf16x8*)((char*)Ks + KL[it]) = kreg[it];
      *(bf16x8*)((char*)Vs + VL[it]) = vreg[it];
    }
    __syncthreads();
    if (kt + 1 < ntk) {
#pragma unroll
      for (int it = 0; it < 4; ++it) {
        kreg[it] = *(const bf16x8*)(Kg0 + (size_t)((kt + 1) * 128 + Kro[it]) * 6144 + Kcb[it]);
        vreg[it] = *(const bf16x8*)(Vg0 + (kt + 1) * 256 + Voff[it]);
      }
    }

    f32x4 sf[8];
#pragma unroll
    for (int cf = 0; cf < 8; ++cf) {
      f32x4 z = {};
#pragma unroll
      for (int ks = 0; ks < 2; ++ks) {
        int P = (cf * 16 + l15) * 128 + (ks * 32 + l4 * 8) * 2;
        bf16x8 kb = *(const bf16x8*)((const char*)Ks + (P ^ (((P >> 7) & 7) << 4)));
        z = __builtin_amdgcn_mfma_f32_16x16x32_bf16(aq[ks], kb, z, 0, 0, 0);
      }
      sf[cf] = z;
    }
    if (kt == ntk - 1) {
#pragma unroll
      for (int cf = 0; cf < 8; ++cf)
#pragma unroll
        for (int r = 0; r < 4; ++r) {
          int kg = kt * 128 + cf * 16 + l15;
          int qg = q0 + wid * 16 + l4 * 4 + r;
          if (kg > qg) sf[cf][r] = -1e30f;
        }
    }
    float fac[4];
#pragma unroll
    for (int r = 0; r < 4; ++r) {
      float tm = fmaxf(fmaxf(fmaxf(sf[0][r], sf[1][r]), fmaxf(sf[2][r], sf[3][r])),
                       fmaxf(fmaxf(sf[4][r], sf[5][r]), fmaxf(sf[6][r], sf[7][r])));
#pragma unroll
      for (int off = 1; off < 16; off <<= 1) tm = fmaxf(tm, __shfl_xor(tm, off));
      if (tm > m_run[r] + 64.f) {
        fac[r] = exp2f((m_run[r] - tm) * CEXP);
        m_run[r] = tm;
      } else {
        fac[r] = 1.f;
      }
      float ps = 0.f;
#pragma unroll
      for (int cf = 0; cf < 8; ++cf) {
        float p = exp2f((sf[cf][r] - m_run[r]) * CEXP);
        sf[cf][r] = p;
        ps += p;
      }
      l_part[r] = l_part[r] * fac[r] + ps;
    }
#pragma unroll
    for (int cf = 0; cf < 8; ++cf)
#pragma unroll
      for (int r = 0; r < 4; ++r)
        Ps[wid][(l4 * 4 + r) * 136 + cf * 16 + l15] = f2bf(sf[cf][r]);
#pragma unroll
    for (int hf = 0; hf < 4; ++hf)
#pragma unroll
      for (int r = 0; r < 4; ++r) o[hf][r] *= fac[r];
    bf16x8 pa[4];
#pragma unroll
    for (int ks = 0; ks < 4; ++ks)
      pa[ks] = *(const bf16x8*)&Ps[wid][l15 * 136 + ks * 32 + l4 * 8];
#pragma unroll
    for (int hf = 0; hf < 4; ++hf) {
#pragma unroll
      for (int ks = 0; ks < 4; ++ks) {
        int P = (hf * 16 + l15) * 256 + (ks * 32 + l4 * 8) * 2;
        bf16x8 vb = *(const bf16x8*)((const char*)Vs + (P ^ (((P >> 8) & 7) << 4)));
        o[hf] = __builtin_amdgcn_mfma_f32_16x16x32_bf16(pa[ks], vb, o[hf], 0, 0, 0);
      }
    }
    __syncthreads();
  }
  float lsum[4];
#pragma unroll
  for (int r = 0; r < 4; ++r) {
    float s = l_part[r];
#pragma unroll
    for (int off = 1; off < 16; off <<= 1) s += __shfl_xor(s, off);
    lsum[r] = s;
  }
#pragma unroll
  for (int hf = 0; hf < 4; ++hf)
#pragma unroll
    for (int r = 0; r < 4; ++r) {
      float val = o[hf][r] / lsum[r];
      size_t row = (size_t)b * TTT + q0 + wid * 16 + l4 * 4 + r;
      attout[row * DD + nh * 64 + hf * 16 + l15] = f2bf(val);
    }
}

// ---------------- lm head: sum bf16 proj partials + final LN + tied head ----------------
__global__ __launch_bounds__(256) void k_head(const float* __restrict__ x,
                                              const u16* __restrict__ pp, int npart,
                                              const float* __restrict__ lnf_w,
                                              const float* __restrict__ lnf_b,
                                              const float* __restrict__ wte,
                                              float* __restrict__ out) {
  __shared__ float xs[2 * DD];
  __shared__ float sm[8];
  int tid = threadIdx.x;
  int wid = tid >> 6, lane = tid & 63;
#pragma unroll
  for (int bb = 0; bb < 2; ++bb) {
    int m = bb * TTT + (TTT - 1);
    float4 v = *(const float4*)(x + (size_t)m * DD + tid * 4);
#pragma unroll 4
    for (int p = 0; p < npart; ++p) {
      uint64_t pv = *(const uint64_t*)(pp + (size_t)p * MR * DD + (size_t)m * DD + tid * 4);
      v.x += bf2f((u16)(pv));
      v.y += bf2f((u16)(pv >> 16));
      v.z += bf2f((u16)(pv >> 32));
      v.w += bf2f((u16)(pv >> 48));
    }
    float s = v.x + v.y + v.z + v.w;
    float q = v.x * v.x + v.y * v.y + v.z * v.z + v.w * v.w;
#pragma unroll
    for (int off = 1; off < 64; off <<= 1) { s += __shfl_xor(s, off); q += __shfl_xor(q, off); }
    if ((tid & 63) == 0) { sm[wid] = s; sm[4 + wid] = q; }
    __syncthreads();
    s = sm[0] + sm[1] + sm[2] + sm[3];
    q = sm[4] + sm[5] + sm[6] + sm[7];
    float mean = s * (1.f / DD);
    float var = q * (1.f / DD) - mean * mean;
    float rs = rsqrtf(var + 1e-5f);
    const float4 wv = *(const float4*)(lnf_w + tid * 4);
    const float4 bv = *(const float4*)(lnf_b + tid * 4);
    float4 o;
    o.x = (v.x - mean) * rs * wv.x + bv.x;
    o.y = (v.y - mean) * rs * wv.y + bv.y;
    o.z = (v.z - mean) * rs * wv.z + bv.z;
    o.w = (v.w - mean) * rs * wv.w + bv.w;
    *(float4*)(xs + bb * DD + tid * 4) = o;
    __syncthreads();
  }
  for (int v = blockIdx.x * 4 + wid; v < VVV; v += gridDim.x * 4) {
    const float* wr = wte + (size_t)v * DD;
    float a0 = 0.f, a1 = 0.f;
#pragma unroll
    for (int j = 0; j < 4; ++j) {
      const float4 wv = *(const float4*)(wr + lane * 16 + j * 4);
      const float4 x0 = *(const float4*)(xs + lane * 16 + j * 4);
      const float4 x1 = *(const float4*)(xs + DD + lane * 16 + j * 4);
      a0 += wv.x * x0.x + wv.y * x0.y + wv.z * x0.z + wv.w * x0.w;
      a1 += wv.x * x1.x + wv.y * x1.y + wv.z * x1.z + wv.w * x1.w;
    }
#pragma unroll
    for (int off = 1; off < 64; off <<= 1) { a0 += __shfl_xor(a0, off); a1 += __shfl_xor(a1, off); }
    if (lane == 0) { out[v] = a0; out[VVV + v] = a1; }
  }
}

extern "C" void kernel_launch(void* const* d_in, const int* in_sizes, int n_in,
                              void* d_out, int out_size, void* d_ws, size_t ws_size,
                              hipStream_t stream) {
  const int* tokens    = (const int*)d_in[0];
  const float* wte     = (const float*)d_in[1];
  const float* wpe     = (const float*)d_in[2];
  const float* ln1_w   = (const float*)d_in[3];
  const float* ln1_b   = (const float*)d_in[4];
  const float* attn_w  = (const float*)d_in[5];
  const float* attn_b  = (const float*)d_in[6];
  const float* aproj_w = (const float*)d_in[7];
  const float* aproj_b = (const float*)d_in[8];
  const float* ln2_w   = (const float*)d_in[9];
  const float* ln2_b   = (const float*)d_in[10];
  const float* fc_w    = (const float*)d_in[11];
  const float* fc_b    = (const float*)d_in[12];
  const float* proj_w  = (const float*)d_in[13];
  const float* proj_b  = (const float*)d_in[14];
  const float* lnf_w   = (const float*)d_in[15];
  const float* lnf_b   = (const float*)d_in[16];

  char* ws = (char*)d_ws;
  float* x    = (float*)(ws);                    // 0..8 MiB
  u16* h      = (u16*)(ws + (8u << 20));         // 8..12
  u16* wt     = (u16*)(ws + (12u << 20));        // 12..36 (atw/apw/fcw/pjw)
  u16* qkv    = (u16*)(ws + (36u << 20));        // 36..48
  u16* Vt     = (u16*)(ws + (52u << 20));        // 52..56
  u16* attb   = (u16*)(ws + (56u << 20));        // 56..60
  u16* mlph   = (u16*)(ws + (36u << 20));        // 36..52 (aliases dead qkv)
  u16* pp     = (u16*)(ws + (60u << 20));        // 60..76 (4x 4MB bf16 partials)
  float* pbias = (float*)(ws + (92u << 20));     // 92 MiB + 12 KB
  float* out  = (float*)d_out;

  u16* atw = wt;
  u16* apw = wt + 3145728;
  u16* fcw = wt + 4194304;
  u16* pjw = wt + 8388608;

  k_embed<<<MR, 256, 0, stream>>>(tokens, wte, wpe, x);

  for (int l = 0; l < 12; ++l) {
    k_prep<<<3585, 256, 0, stream>>>(x, pp, l == 0 ? 0 : 4,
                                     ln1_w + l * DD, ln1_b + l * DD, h,
                                     attn_w + (size_t)l * DD * 3 * DD,
                                     aproj_w + (size_t)l * DD * DD,
                                     fc_w + (size_t)l * DD * FFF,
                                     proj_w + (size_t)l * FFF * DD, wt,
                                     attn_b + (size_t)l * 3 * DD, pbias);
    k_gemm<0, 64><<<dim3(16, 48, 1), 256, 0, stream>>>(h, atw, pbias, qkv, nullptr, Vt, MR, 3072, 1024, 1024);
    k_attn<<<dim3(32, 16), 256, 0, stream>>>(qkv, Vt, attb);
    k_gemm<4, 128><<<dim3(16, 8, 4), 256, 0, stream>>>(attb, apw, aproj_b + (size_t)l * DD, nullptr, pp, nullptr, MR, 1024, 1024, 256);
    k_addln<<<512, 256, 0, stream>>>(x, pp, 4, ln2_w + l * DD, ln2_b + l * DD, h);
    k_gemm<2, 128><<<dim3(16, 32, 1), 256, 0, stream>>>(h, fcw, fc_b + (size_t)l * FFF, mlph, nullptr, nullptr, MR, 4096, 1024, 1024);
    k_gemm<4, 128><<<dim3(16, 8, 4), 256, 0, stream>>>(mlph, pjw, proj_b + (size_t)l * DD, nullptr, pp, nullptr, MR, 1024, 4096, 1024);
  }
  k_head<<<512, 256, 0, stream>>>(x, pp, 4, lnf_w, lnf_b, wte, out);
}

// Round 17
// 1732.074 us; speedup vs baseline: 1.0320x; 1.0320x over previous
//
#include <hip/hip_runtime.h>
#include <cstdint>
#include <math.h>

// GPT-2 forward, MI355X. B=2, T=1024, D=1024, NH=16, HD=64, L=12, F=4096, V=50257.
// fp32 residual; bf16 MFMA GEMMs (128^2 tile, 16x16x32, 2-deep counted-vmcnt
// pipeline, T2 XOR swizzle, setprio, XCD swizzle); LDS-bounce epilogue with fused
// V-transpose in the qkv GEMM; bf16 split-K(x2) partials summed in next LN;
// head-major qkv; reg-staged attn; embed+wtrans+bias-permute fused into prep.

using u16 = unsigned short;
using bf16x8 = __attribute__((ext_vector_type(8))) short;
using f32x4 = __attribute__((ext_vector_type(4))) float;

#define GLDS16(g, l)                                                        \
  __builtin_amdgcn_global_load_lds(                                         \
      (const __attribute__((address_space(1))) void*)(g),                   \
      (__attribute__((address_space(3))) void*)(l), 16, 0, 0)

__device__ __forceinline__ u16 f2bf(float f) {
  union { float f; unsigned u; } t; t.f = f;
  unsigned r = t.u + 0x7fffu + ((t.u >> 16) & 1u);
  return (u16)(r >> 16);
}
__device__ __forceinline__ float bf2f(u16 v) {
  union { unsigned u; float f; } t; t.u = ((unsigned)v) << 16;
  return t.f;
}

// A&S 7.1.26, |err| <= 1.5e-7
__device__ __forceinline__ float fast_erf(float x) {
  float ax = fabsf(x);
  float t = 1.f / (1.f + 0.3275911f * ax);
  float y = t * (0.254829592f +
            t * (-0.284496736f +
            t * (1.421413741f +
            t * (-1.453152027f +
            t * 1.061405429f))));
  float r = 1.f - y * __expf(-ax * ax);
  return copysignf(r, x);
}

#define DD 1024
#define TTT 1024
#define MR 2048     // B*T
#define FFF 4096
#define VVV 50257

// ---------------- add bf16 partials (or embed) + layernorm -> bf16 ----------------
__device__ __forceinline__ void addln_body(float* __restrict__ x,
                                           const u16* __restrict__ pp, int npart,
                                           const float* __restrict__ w,
                                           const float* __restrict__ b,
                                           u16* __restrict__ out, int blk,
                                           const int* __restrict__ tokens,
                                           const float* __restrict__ wte,
                                           const float* __restrict__ wpe,
                                           int emb) {
  const int wid = threadIdx.x >> 6, lane = threadIdx.x & 63;
  const int m = blk * 4 + wid;
  float* row = x + (size_t)m * DD;
  float4 v[4];
  float s = 0.f, q = 0.f;
  if (emb) {
    const int tok = tokens[m];
    const int t = m & (TTT - 1);
#pragma unroll
    for (int j = 0; j < 4; ++j) {
      const float4 a = *(const float4*)(wte + (size_t)tok * DD + j * 256 + lane * 4);
      const float4 p = *(const float4*)(wpe + (size_t)t * DD + j * 256 + lane * 4);
      v[j].x = a.x + p.x; v[j].y = a.y + p.y; v[j].z = a.z + p.z; v[j].w = a.w + p.w;
      *(float4*)(row + j * 256 + lane * 4) = v[j];
      s += v[j].x + v[j].y + v[j].z + v[j].w;
      q += v[j].x * v[j].x + v[j].y * v[j].y + v[j].z * v[j].z + v[j].w * v[j].w;
    }
  } else {
#pragma unroll
    for (int j = 0; j < 4; ++j) {
      v[j] = *(const float4*)(row + j * 256 + lane * 4);
#pragma unroll 2
      for (int p = 0; p < npart; ++p) {
        uint64_t pv = *(const uint64_t*)(pp + (size_t)p * MR * DD + (size_t)m * DD + j * 256 + lane * 4);
        v[j].x += bf2f((u16)(pv));
        v[j].y += bf2f((u16)(pv >> 16));
        v[j].z += bf2f((u16)(pv >> 32));
        v[j].w += bf2f((u16)(pv >> 48));
      }
      if (npart) *(float4*)(row + j * 256 + lane * 4) = v[j];
      s += v[j].x + v[j].y + v[j].z + v[j].w;
      q += v[j].x * v[j].x + v[j].y * v[j].y + v[j].z * v[j].z + v[j].w * v[j].w;
    }
  }
#pragma unroll
  for (int off = 1; off < 64; off <<= 1) { s += __shfl_xor(s, off); q += __shfl_xor(q, off); }
  float mean = s * (1.f / DD);
  float var = q * (1.f / DD) - mean * mean;
  float rs = rsqrtf(var + 1e-5f);
#pragma unroll
  for (int j = 0; j < 4; ++j) {
    const float4 wv = *(const float4*)(w + j * 256 + lane * 4);
    const float4 bv = *(const float4*)(b + j * 256 + lane * 4);
    u16 o[4];
    o[0] = f2bf((v[j].x - mean) * rs * wv.x + bv.x);
    o[1] = f2bf((v[j].y - mean) * rs * wv.y + bv.y);
    o[2] = f2bf((v[j].z - mean) * rs * wv.z + bv.z);
    o[3] = f2bf((v[j].w - mean) * rs * wv.w + bv.w);
    *(uint64_t*)(out + (size_t)m * DD + j * 256 + lane * 4) = *(uint64_t*)o;
  }
}

__global__ __launch_bounds__(256) void k_addln(float* __restrict__ x,
                                               const u16* __restrict__ pp, int npart,
                                               const float* __restrict__ w,
                                               const float* __restrict__ b,
                                               u16* __restrict__ out) {
  addln_body(x, pp, npart, w, b, out, blockIdx.x, nullptr, nullptr, nullptr, 0);
}

// ---------------- weight transpose body: fp32[K,N] -> bf16[N,K] ----------------
// atw rows are stored head-major-permuted: c = part*1024 + n*64 + h.
__device__ __forceinline__ void wtrans_body(const float* __restrict__ atw,
                                            const float* __restrict__ apw,
                                            const float* __restrict__ fcw,
                                            const float* __restrict__ pjw,
                                            u16* __restrict__ wt, int id) {
  __shared__ u16 tb[64][72];
  const float* W; u16* Wt; int K, N, local, kts; bool perm = false;
  if (id < 768)       { W = atw; Wt = wt;           K = 1024; N = 3072; local = id;        kts = 4; perm = true; }
  else if (id < 1024) { W = apw; Wt = wt + 3145728; K = 1024; N = 1024; local = id - 768;  kts = 4; }
  else if (id < 2048) { W = fcw; Wt = wt + 4194304; K = 1024; N = 4096; local = id - 1024; kts = 4; }
  else                { W = pjw; Wt = wt + 8388608; K = 4096; N = 1024; local = id - 2048; kts = 6; }
  const int k0 = (local & ((1 << kts) - 1)) * 64, n0 = (local >> kts) * 64;
  const int tid = threadIdx.x;
  const int rr = tid >> 4, c4 = (tid & 15) * 4;
#pragma unroll
  for (int i = 0; i < 4; ++i) {
    const int r = rr + i * 16;
    const float4 v = *(const float4*)(W + (size_t)(k0 + r) * N + n0 + c4);
    tb[c4 + 0][r] = f2bf(v.x);
    tb[c4 + 1][r] = f2bf(v.y);
    tb[c4 + 2][r] = f2bf(v.z);
    tb[c4 + 3][r] = f2bf(v.w);
  }
  __syncthreads();
  const int n = tid >> 3, k8 = (tid & 7) * 8;
#pragma unroll
  for (int s = 0; s < 2; ++s) {
    u16 o[8];
#pragma unroll
    for (int j = 0; j < 8; ++j) o[j] = tb[n + s * 32][k8 + j];
    int orow = n0 + n + s * 32;
    if (perm) {
      int part = orow >> 10, w = orow & 1023;
      orow = part * 1024 + (w & 15) * 64 + (w >> 4);
    }
    *(bf16x8*)(Wt + (size_t)orow * K + k0 + k8) = *(bf16x8*)o;
  }
}

// ---------------- fused prep: [0,512) (embed|add)+LN1, 3584 bias-permute, else wtrans ----------------
__global__ __launch_bounds__(256) void k_prep(float* __restrict__ x,
                                              const u16* __restrict__ pp, int npart,
                                              const float* __restrict__ w,
                                              const float* __restrict__ b,
                                              u16* __restrict__ out,
                                              const float* __restrict__ atw,
                                              const float* __restrict__ apw,
                                              const float* __restrict__ fcw,
                                              const float* __restrict__ pjw,
                                              u16* __restrict__ wt,
                                              const float* __restrict__ ab,
                                              float* __restrict__ pbias,
                                              const int* __restrict__ tokens,
                                              const float* __restrict__ wte,
                                              const float* __restrict__ wpe,
                                              int emb) {
  if (blockIdx.x < 512) {
    addln_body(x, pp, npart, w, b, out, blockIdx.x, tokens, wte, wpe, emb);
  } else if (blockIdx.x == 3584) {
    for (int c = threadIdx.x; c < 3072; c += 256) {
      int part = c >> 10, ww = c & 1023;
      pbias[c] = ab[part * 1024 + (ww & 63) * 16 + (ww >> 6)];
    }
  } else {
    wtrans_body(atw, apw, fcw, pjw, wt, blockIdx.x - 512);
  }
}

// ---------------- GEMM: out = A[M,K] * Bt[N,K]^T + bias (R15 config) ----------------
// EPI 0: bf16 out + fused V-transpose (by>=16 -> Vt, no normal store);
// EPI 2: gelu->bf16; EPI 4: bf16 partial (split-K, bias bz==0).
template <int EPI>
__global__ __launch_bounds__(256) void k_gemm(const u16* __restrict__ A,
                                              const u16* __restrict__ Bt,
                                              const float* __restrict__ bias,
                                              u16* __restrict__ outb,
                                              u16* __restrict__ pp,
                                              u16* __restrict__ vt,
                                              int M, int N, int K, int KC) {
  __shared__ u16 smem[4][128 * 64];   // [0..1]=A dbuf, [2..3]=B dbuf; epilogue aliases
  // bijective XCD swizzle (m204)
  const int nbx = gridDim.x, nby = gridDim.y;
  const int nwg = nbx * nby * gridDim.z;
  const int orig = blockIdx.x + nbx * (blockIdx.y + nby * blockIdx.z);
  const int qq = nwg >> 3, rr = nwg & 7;
  const int xcd = orig & 7, pos = orig >> 3;
  const int wg = (xcd < rr ? xcd * (qq + 1) : rr * (qq + 1) + (xcd - rr) * qq) + pos;
  const int bx = wg % nbx;
  const int tmpw = wg / nbx;
  const int by = tmpw % nby, bz = tmpw / nby;

  const int tid = threadIdx.x;
  const int lane = tid & 63, wid = tid >> 6;
  const int wr = wid >> 1, wc = wid & 1;
  const int l15 = lane & 15, l4 = lane >> 4;
  const int sx = l15 & 7;
  const int m0 = bx * 128, n0 = by * 128;
  f32x4 acc[4][4] = {};

  const int srow = tid >> 3;
  const int scol = (((tid & 7) ^ (srow & 7)) * 8);  // inverse swizzle on source
  const int k0beg = bz * KC;
  const int nt = KC >> 6;

  const u16* Ap = A + (size_t)(m0 + srow) * K + scol;
  const u16* Bp = Bt + (size_t)(n0 + srow) * K + scol;

#define STAGE(buf, k0)                                                      \
  {                                                                         \
    _Pragma("unroll")                                                       \
    for (int it = 0; it < 4; ++it) {                                        \
      GLDS16(Ap + (size_t)it * 32 * K + (k0), (char*)smem[buf] + it * 4096 + tid * 16); \
      GLDS16(Bp + (size_t)it * 32 * K + (k0), (char*)smem[2 + (buf)] + it * 4096 + tid * 16); \
    }                                                                       \
  }

  STAGE(0, k0beg);
  for (int t = 0; t < nt; ++t) {
    if (t + 1 < nt) {
      STAGE((t + 1) & 1, k0beg + (t + 1) * 64);
      asm volatile("s_waitcnt vmcnt(8)" ::: "memory");
    } else {
      asm volatile("s_waitcnt vmcnt(0)" ::: "memory");
    }
    __builtin_amdgcn_sched_barrier(0);
    __builtin_amdgcn_s_barrier();
    __builtin_amdgcn_sched_barrier(0);
    const u16* Ab = smem[t & 1];
    const u16* Bb = smem[2 + (t & 1)];
#pragma unroll
    for (int ks = 0; ks < 2; ++ks) {
      const int ch = ((ks * 4 + l4) ^ sx) * 8;
      bf16x8 af[4], bfr[4];
#pragma unroll
      for (int i = 0; i < 4; ++i)
        af[i] = *(const bf16x8*)(Ab + (wr * 64 + i * 16 + l15) * 64 + ch);
#pragma unroll
      for (int j = 0; j < 4; ++j)
        bfr[j] = *(const bf16x8*)(Bb + (wc * 64 + j * 16 + l15) * 64 + ch);
      __builtin_amdgcn_s_setprio(1);
#pragma unroll
      for (int i = 0; i < 4; ++i)
#pragma unroll
        for (int j = 0; j < 4; ++j)
          acc[i][j] = __builtin_amdgcn_mfma_f32_16x16x32_bf16(af[i], bfr[j], acc[i][j], 0, 0, 0);
      __builtin_amdgcn_s_setprio(0);
    }
    __builtin_amdgcn_sched_barrier(0);
    __builtin_amdgcn_s_barrier();
    __builtin_amdgcn_sched_barrier(0);
  }
#undef STAGE
  // ---- LDS-bounce epilogue (staging buffers are free past the final barrier) ----
  u16* eb = (u16*)smem;  // [128][132] bf16
#pragma unroll
  for (int j = 0; j < 4; ++j) {
    const int col = wc * 64 + j * 16 + l15;
    const float bs = (EPI == 4 && bz != 0) ? 0.f : bias[n0 + col];
#pragma unroll
    for (int i = 0; i < 4; ++i) {
#pragma unroll
      for (int r = 0; r < 4; ++r) {
        const int row = wr * 64 + i * 16 + l4 * 4 + r;
        float v = acc[i][j][r] + bs;
        if (EPI == 2) v = 0.5f * v * (1.f + fast_erf(v * 0.70710678118f));
        eb[row * 132 + col] = f2bf(v);
      }
    }
  }
  __syncthreads();
  if (EPI == 0 && by >= 16) {
    // fused V-transpose: tile cols are V-part (head-major); write Vt[bn*64+h][t]
    const int b = m0 >> 10, t0 = m0 & 1023;
    const int col = tid >> 1;           // 0..127
    const int tseg = tid & 1;           // 0..1
    const int gc = n0 + col - 2048;
    const int n = gc >> 6, hh = gc & 63;
    u16* vdst = vt + (((size_t)(b * 16 + n)) * 64 + hh) * TTT + t0 + tseg * 64;
    const u16* es = eb + (tseg * 64) * 132 + col;
#pragma unroll
    for (int s = 0; s < 8; ++s) {
      u16 o[8];
#pragma unroll
      for (int k = 0; k < 8; ++k) o[k] = es[(s * 8 + k) * 132];
      *(bf16x8*)(vdst + s * 8) = *(bf16x8*)o;
    }
  } else {
    const int erow = tid >> 1;
    const int ecol0 = (tid & 1) * 64;
    u16* gout = (EPI == 4) ? (pp + (size_t)bz * M * N) : outb;
    u16* gdst = gout + (size_t)(m0 + erow) * N + n0 + ecol0;
    const u16* esrc = eb + erow * 132 + ecol0;
#pragma unroll
    for (int c = 0; c < 8; ++c)
      *(bf16x8*)(gdst + c * 8) = *(const bf16x8*)(esrc + c * 8);
  }
}

// ---------------- flash attention (causal), T14 reg-staged K/V ----------------
__global__ __launch_bounds__(256) void k_attn(const u16* __restrict__ qkv,
                                              const u16* __restrict__ Vt,
                                              u16* __restrict__ attout) {
  __shared__ u16 Ks[128 * 64];
  __shared__ u16 Vs[64 * 128];
  __shared__ u16 Ps[4][16 * 136];

  const int tid = threadIdx.x;
  const int lane = tid & 63, wid = tid >> 6;
  const int l15 = lane & 15, l4 = lane >> 4;
  const int bn = blockIdx.x;                 // b*16 + n
  const int qtr = 15 - (int)blockIdx.y;      // heavy tiles first
  const int q0 = qtr * 64;
  const int b = bn >> 4, nh = bn & 15;
  const char* Kg0 = (const char*)(qkv + (size_t)b * TTT * 3072 + 1024 + nh * 64);
  const char* Vg0 = (const char*)(Vt + (size_t)bn * 64 * TTT);
  const float CEXP = 0.125f * 1.44269504f;   // fold scale into exp2

  int KL[4], Kro[4], Kcb[4], VL[4], Voff[4];
#pragma unroll
  for (int it = 0; it < 4; ++it) {
    int L = it * 4096 + tid * 16;
    KL[it] = L;
    int Ls = L ^ (((L >> 7) & 7) << 4);
    Kro[it] = Ls >> 7; Kcb[it] = Ls & 127;
    VL[it] = L;
    int Ls2 = L ^ (((L >> 8) & 7) << 4);
    Voff[it] = (Ls2 >> 8) * 2048 + (Ls2 & 255);
  }

  const int qrow = q0 + wid * 16 + l15;
  const u16* qsrc = qkv + (size_t)(b * TTT + qrow) * 3072 + nh * 64;
  bf16x8 aq[2];
#pragma unroll
  for (int ks = 0; ks < 2; ++ks)
    aq[ks] = *(const bf16x8*)(qsrc + ks * 32 + l4 * 8);

  float m_run[4], l_part[4];
  f32x4 o[4] = {};
#pragma unroll
  for (int r = 0; r < 4; ++r) { m_run[r] = -1e30f; l_part[r] = 0.f; }

  const int ntk = (qtr >> 1) + 1;
  bf16x8 kreg[4], vreg[4];
#pragma unroll
  for (int it = 0; it < 4; ++it) {
    kreg[it] = *(const bf16x8*)(Kg0 + (size_t)Kro[it] * 6144 + Kcb[it]);
    vreg[it] = *(const bf16x8*)(Vg0 + Voff[it]);
  }
  for (int kt = 0; kt < ntk; ++kt) {
#pragma unroll
    for (int it = 0; it < 4; ++it) {
      *(bf16x8*)((char*)Ks + KL[it]) = kreg[it];
      *(bf16x8*)((char*)Vs + VL[it]) = vreg[it];
    }
    __syncthreads();
    if (kt + 1 < ntk) {
#pragma unroll
      for (int it = 0; it < 4; ++it) {
        kreg[it] = *(const bf16x8*)(Kg0 + (size_t)((kt + 1) * 128 + Kro[it]) * 6144 + Kcb[it]);
        vreg[it] = *(const bf16x8*)(Vg0 + (kt + 1) * 256 + Voff[it]);
      }
    }

    f32x4 sf[8];
#pragma unroll
    for (int cf = 0; cf < 8; ++cf) {
      f32x4 z = {};
#pragma unroll
      for (int ks = 0; ks < 2; ++ks) {
        int P = (cf * 16 + l15) * 128 + (ks * 32 + l4 * 8) * 2;
        bf16x8 kb = *(const bf16x8*)((const char*)Ks + (P ^ (((P >> 7) & 7) << 4)));
        z = __builtin_amdgcn_mfma_f32_16x16x32_bf16(aq[ks], kb, z, 0, 0, 0);
      }
      sf[cf] = z;
    }
    if (kt == ntk - 1) {
#pragma unroll
      for (int cf = 0; cf < 8; ++cf)
#pragma unroll
        for (int r = 0; r < 4; ++r) {
          int kg = kt * 128 + cf * 16 + l15;
          int qg = q0 + wid * 16 + l4 * 4 + r;
          if (kg > qg) sf[cf][r] = -1e30f;
        }
    }
    float fac[4];
#pragma unroll
    for (int r = 0; r < 4; ++r) {
      float tm = fmaxf(fmaxf(fmaxf(sf[0][r], sf[1][r]), fmaxf(sf[2][r], sf[3][r])),
                       fmaxf(fmaxf(sf[4][r], sf[5][r]), fmaxf(sf[6][r], sf[7][r])));
#pragma unroll
      for (int off = 1; off < 16; off <<= 1) tm = fmaxf(tm, __shfl_xor(tm, off));
      if (tm > m_run[r] + 64.f) {
        fac[r] = exp2f((m_run[r] - tm) * CEXP);
        m_run[r] = tm;
      } else {
        fac[r] = 1.f;
      }
      float ps = 0.f;
#pragma unroll
      for (int cf = 0; cf < 8; ++cf) {
        float p = exp2f((sf[cf][r] - m_run[r]) * CEXP);
        sf[cf][r] = p;
        ps += p;
      }
      l_part[r] = l_part[r] * fac[r] + ps;
    }
#pragma unroll
    for (int cf = 0; cf < 8; ++cf)
#pragma unroll
      for (int r = 0; r < 4; ++r)
        Ps[wid][(l4 * 4 + r) * 136 + cf * 16 + l15] = f2bf(sf[cf][r]);
#pragma unroll
    for (int hf = 0; hf < 4; ++hf)
#pragma unroll
      for (int r = 0; r < 4; ++r) o[hf][r] *= fac[r];
    bf16x8 pa[4];
#pragma unroll
    for (int ks = 0; ks < 4; ++ks)
      pa[ks] = *(const bf16x8*)&Ps[wid][l15 * 136 + ks * 32 + l4 * 8];
#pragma unroll
    for (int hf = 0; hf < 4; ++hf) {
#pragma unroll
      for (int ks = 0; ks < 4; ++ks) {
        int P = (hf * 16 + l15) * 256 + (ks * 32 + l4 * 8) * 2;
        bf16x8 vb = *(const bf16x8*)((const char*)Vs + (P ^ (((P >> 8) & 7) << 4)));
        o[hf] = __builtin_amdgcn_mfma_f32_16x16x32_bf16(pa[ks], vb, o[hf], 0, 0, 0);
      }
    }
    __syncthreads();
  }
  float lsum[4];
#pragma unroll
  for (int r = 0; r < 4; ++r) {
    float s = l_part[r];
#pragma unroll
    for (int off = 1; off < 16; off <<= 1) s += __shfl_xor(s, off);
    lsum[r] = s;
  }
#pragma unroll
  for (int hf = 0; hf < 4; ++hf)
#pragma unroll
    for (int r = 0; r < 4; ++r) {
      float val = o[hf][r] / lsum[r];
      size_t row = (size_t)b * TTT + q0 + wid * 16 + l4 * 4 + r;
      attout[row * DD + nh * 64 + hf * 16 + l15] = f2bf(val);
    }
}

// ---------------- lm head: sum bf16 proj partials + final LN + tied head ----------------
__global__ __launch_bounds__(256) void k_head(const float* __restrict__ x,
                                              const u16* __restrict__ pp, int npart,
                                              const float* __restrict__ lnf_w,
                                              const float* __restrict__ lnf_b,
                                              const float* __restrict__ wte,
                                              float* __restrict__ out) {
  __shared__ float xs[2 * DD];
  __shared__ float sm[8];
  int tid = threadIdx.x;
  int wid = tid >> 6, lane = tid & 63;
#pragma unroll
  for (int bb = 0; bb < 2; ++bb) {
    int m = bb * TTT + (TTT - 1);
    float4 v = *(const float4*)(x + (size_t)m * DD + tid * 4);
#pragma unroll 2
    for (int p = 0; p < npart; ++p) {
      uint64_t pv = *(const uint64_t*)(pp + (size_t)p * MR * DD + (size_t)m * DD + tid * 4);
      v.x += bf2f((u16)(pv));
      v.y += bf2f((u16)(pv >> 16));
      v.z += bf2f((u16)(pv >> 32));
      v.w += bf2f((u16)(pv >> 48));
    }
    float s = v.x + v.y + v.z + v.w;
    float q = v.x * v.x + v.y * v.y + v.z * v.z + v.w * v.w;
#pragma unroll
    for (int off = 1; off < 64; off <<= 1) { s += __shfl_xor(s, off); q += __shfl_xor(q, off); }
    if ((tid & 63) == 0) { sm[wid] = s; sm[4 + wid] = q; }
    __syncthreads();
    s = sm[0] + sm[1] + sm[2] + sm[3];
    q = sm[4] + sm[5] + sm[6] + sm[7];
    float mean = s * (1.f / DD);
    float var = q * (1.f / DD) - mean * mean;
    float rs = rsqrtf(var + 1e-5f);
    const float4 wv = *(const float4*)(lnf_w + tid * 4);
    const float4 bv = *(const float4*)(lnf_b + tid * 4);
    float4 o;
    o.x = (v.x - mean) * rs * wv.x + bv.x;
    o.y = (v.y - mean) * rs * wv.y + bv.y;
    o.z = (v.z - mean) * rs * wv.z + bv.z;
    o.w = (v.w - mean) * rs * wv.w + bv.w;
    *(float4*)(xs + bb * DD + tid * 4) = o;
    __syncthreads();
  }
  for (int v = blockIdx.x * 4 + wid; v < VVV; v += gridDim.x * 4) {
    const float* wr = wte + (size_t)v * DD;
    float a0 = 0.f, a1 = 0.f;
#pragma unroll
    for (int j = 0; j < 4; ++j) {
      const float4 wv = *(const float4*)(wr + lane * 16 + j * 4);
      const float4 x0 = *(const float4*)(xs + lane * 16 + j * 4);
      const float4 x1 = *(const float4*)(xs + DD + lane * 16 + j * 4);
      a0 += wv.x * x0.x + wv.y * x0.y + wv.z * x0.z + wv.w * x0.w;
      a1 += wv.x * x1.x + wv.y * x1.y + wv.z * x1.z + wv.w * x1.w;
    }
#pragma unroll
    for (int off = 1; off < 64; off <<= 1) { a0 += __shfl_xor(a0, off); a1 += __shfl_xor(a1, off); }
    if (lane == 0) { out[v] = a0; out[VVV + v] = a1; }
  }
}

extern "C" void kernel_launch(void* const* d_in, const int* in_sizes, int n_in,
                              void* d_out, int out_size, void* d_ws, size_t ws_size,
                              hipStream_t stream) {
  const int* tokens    = (const int*)d_in[0];
  const float* wte     = (const float*)d_in[1];
  const float* wpe     = (const float*)d_in[2];
  const float* ln1_w   = (const float*)d_in[3];
  const float* ln1_b   = (const float*)d_in[4];
  const float* attn_w  = (const float*)d_in[5];
  const float* attn_b  = (const float*)d_in[6];
  const float* aproj_w = (const float*)d_in[7];
  const float* aproj_b = (const float*)d_in[8];
  const float* ln2_w   = (const float*)d_in[9];
  const float* ln2_b   = (const float*)d_in[10];
  const float* fc_w    = (const float*)d_in[11];
  const float* fc_b    = (const float*)d_in[12];
  const float* proj_w  = (const float*)d_in[13];
  const float* proj_b  = (const float*)d_in[14];
  const float* lnf_w   = (const float*)d_in[15];
  const float* lnf_b   = (const float*)d_in[16];

  char* ws = (char*)d_ws;
  float* x    = (float*)(ws);                    // 0..8 MiB
  u16* h      = (u16*)(ws + (8u << 20));         // 8..12
  u16* wt     = (u16*)(ws + (12u << 20));        // 12..36 (atw/apw/fcw/pjw)
  u16* qkv    = (u16*)(ws + (36u << 20));        // 36..48
  u16* Vt     = (u16*)(ws + (52u << 20));        // 52..56
  u16* attb   = (u16*)(ws + (56u << 20));        // 56..60
  u16* mlph   = (u16*)(ws + (36u << 20));        // 36..52 (aliases dead qkv)
  u16* pp     = (u16*)(ws + (60u << 20));        // 60..68 (2x 4MB bf16 partials)
  float* pbias = (float*)(ws + (92u << 20));     // 92 MiB + 12 KB
  float* out  = (float*)d_out;

  u16* atw = wt;
  u16* apw = wt + 3145728;
  u16* fcw = wt + 4194304;
  u16* pjw = wt + 8388608;

  for (int l = 0; l < 12; ++l) {
    k_prep<<<3585, 256, 0, stream>>>(x, pp, 2,
                                     ln1_w + l * DD, ln1_b + l * DD, h,
                                     attn_w + (size_t)l * DD * 3 * DD,
                                     aproj_w + (size_t)l * DD * DD,
                                     fc_w + (size_t)l * DD * FFF,
                                     proj_w + (size_t)l * FFF * DD, wt,
                                     attn_b + (size_t)l * 3 * DD, pbias,
                                     tokens, wte, wpe, l == 0 ? 1 : 0);
    k_gemm<0><<<dim3(16, 24, 1), 256, 0, stream>>>(h, atw, pbias, qkv, nullptr, Vt, MR, 3072, 1024, 1024);
    k_attn<<<dim3(32, 16), 256, 0, stream>>>(qkv, Vt, attb);
    k_gemm<4><<<dim3(16, 8, 2), 256, 0, stream>>>(attb, apw, aproj_b + (size_t)l * DD, nullptr, pp, nullptr, MR, 1024, 1024, 512);
    k_addln<<<512, 256, 0, stream>>>(x, pp, 2, ln2_w + l * DD, ln2_b + l * DD, h);
    k_gemm<2><<<dim3(16, 32, 1), 256, 0, stream>>>(h, fcw, fc_b + (size_t)l * FFF, mlph, nullptr, nullptr, MR, 4096, 1024, 1024);
    k_gemm<4><<<dim3(16, 8, 2), 256, 0, stream>>>(mlph, pjw, proj_b + (size_t)l * DD, nullptr, pp, nullptr, MR, 1024, 4096, 2048);
  }
  k_head<<<512, 256, 0, stream>>>(x, pp, 2, lnf_w, lnf_b, wte, out);
}